// Round 10
// baseline (866.262 us; speedup 1.0000x reference)
//
#include <hip/hip_runtime.h>
#include <stdint.h>

// ---------------- problem constants ----------------
#define OUTC 93
#define KS1 22           // K=704 / 32  (word GEMM k-steps)
#define NPOS 50
#define NDEP 45
// split-path kernel1 tile
#define BM1 256
#define BN1 176
#define NTL 11           // local n-tiles (176/16)
// fused fallback
#define BMF 64
#define H3SF 360         // (unused in fallback; it uses 712 stride internally)

typedef __attribute__((ext_vector_type(8))) short bf16x8;
typedef __attribute__((ext_vector_type(4))) float f32x4;
typedef __attribute__((ext_vector_type(4))) float fvec4;

// ws layout (bytes), all 16B-aligned
#define O_WWP  0
#define SZ_WWP (KS1*44*64*8*2)              // 991,232
#define O_WOP  (O_WWP + SZ_WWP)
#define SZ_WOP (KS1*6*64*8*2)               // 270,336
#define O_PTB  (O_WOP + SZ_WOP)
#define SZ_PTB (7*NPOS*704*2)               // 492,800
#define O_DTB  (O_PTB + SZ_PTB)
#define SZ_DTB (7*NDEP*704*2)               // 443,520
#define O_HB   (O_DTB + SZ_DTB)
#define SZ_HB  (704*4)                      // 2,816
#define O_HW   (O_HB + SZ_HB)               // 2,200,704
#define SZ_HW  ((size_t)65536*704*2)        // 92,274,688
#define WS_NEED_SPLIT (O_HW + SZ_HW)

__device__ __forceinline__ unsigned short f2bf(float f) {
  unsigned u = __float_as_uint(f);
  u += 0x7FFFu + ((u >> 16) & 1u);          // RNE
  return (unsigned short)(u >> 16);
}
__device__ __forceinline__ float bf2f(unsigned short h) {
  return __uint_as_float(((unsigned)h) << 16);
}
__device__ __forceinline__ void addbf8(float* s, const uint4 v) {
  unsigned u0 = v.x, u1 = v.y, u2 = v.z, u3 = v.w;
  s[0] += __uint_as_float(u0 << 16);
  s[1] += __uint_as_float(u0 & 0xFFFF0000u);
  s[2] += __uint_as_float(u1 << 16);
  s[3] += __uint_as_float(u1 & 0xFFFF0000u);
  s[4] += __uint_as_float(u2 << 16);
  s[5] += __uint_as_float(u2 & 0xFFFF0000u);
  s[6] += __uint_as_float(u3 << 16);
  s[7] += __uint_as_float(u3 & 0xFFFF0000u);
}

// ---- prep: pack f32 [Ksrc x Nsrc] into MFMA B-fragment layout [ks][nt][lane][8]
__global__ void pack_w(const float* __restrict__ W, unsigned short* __restrict__ out,
                       int Ksrc, int Nsrc, int ntiles) {
  int blk = blockIdx.x;
  int ks = blk / ntiles, nt = blk - ks*ntiles;
  int l = threadIdx.x;
  int n = nt*16 + (l & 15);
  int k0 = ks*32 + ((l >> 4) << 3);
  unsigned short v[8];
#pragma unroll
  for (int j = 0; j < 8; ++j) {
    int k = k0 + j;
    float f = (k < Ksrc && n < Nsrc) ? W[k*Nsrc + n] : 0.f;
    v[j] = f2bf(f);
  }
  ((uint4*)out)[blk*64 + l] = *(const uint4*)v;
}

// ---- prep: PT[t][p][h] = sum_d tbl[p][d] * W[t*100+d][h], bf16, h padded to 704
__global__ void pack_tbl(const float* __restrict__ tbl, const float* __restrict__ W,
                         unsigned short* __restrict__ out, int P, int total) {
  int id = blockIdx.x*256 + threadIdx.x;
  if (id >= total) return;
  int hp = id % 704;
  int tp = id / 704;
  int p = tp % P, t = tp / P;
  float acc = 0.f;
  if (hp < 700) {
    const float* tr = tbl + p*100;
    const float* wc = W + t*100*700 + hp;
#pragma unroll 4
    for (int d = 0; d < 100; ++d) acc += tr[d] * wc[d*700];
  }
  out[id] = f2bf(acc);
}

__global__ void bias_sum(const float* __restrict__ a, const float* __restrict__ b,
                         const float* __restrict__ c, float* __restrict__ o) {
  int i = blockIdx.x*256 + threadIdx.x;
  if (i < 704) o[i] = (i < 700) ? (a[i] + b[i] + c[i]) : 0.f;
}

// ================= SPLIT PATH kernel 1: hw = gather(word) @ Ww =================
struct SM1 {
  unsigned short A[2][16*64*8];   // 32,768 B
  unsigned short B[2][NTL*64*8];  // 22,528 B
  unsigned short widx[BM1][8];    //  4,096 B  (col 7 = 0xFFFF sentinel pad)
};  // 59,392 B

__launch_bounds__(1024, 4)
__global__ void gemm_hw(const int* __restrict__ word_idx,
                        const float* __restrict__ word_table,
                        const unsigned short* __restrict__ WwP,
                        unsigned short* __restrict__ hw) {
  __shared__ SM1 sm;
  const int tid = threadIdx.x;
  const int lane = tid & 63;
  const int w = tid >> 6;

  // bijective XCD swizzle (1024 % 8 == 0)
  int D = blockIdx.x;
  int g = (D & 7)*128 + (D >> 3);
  const int nb = g & 3;
  const int mb = g >> 2;
  const int rowbase = mb * BM1;

#pragma unroll
  for (int i = tid; i < BM1*8; i += 1024) {
    int r = i >> 3, c = i & 7;
    unsigned short v = 0xFFFFu;
    if (c < 7) {
      int wi = word_idx[(size_t)(rowbase + r)*7 + c];
      v = (wi < 0) ? 0xFFFFu : (unsigned short)wi;
    }
    sm.widx[r][c] = v;
  }

  const int amt  = tid >> 6;
  const int al   = tid & 63;
  const int arow = amt*16 + (al & 15);
  const int akq  = (al >> 4) << 3;

  f32x4 acc[NTL];
#pragma unroll
  for (int j = 0; j < NTL; ++j) acc[j] = (f32x4){0,0,0,0};

  auto issueB = [&](int ks, int bb) {
    const unsigned short* src = WwP + ((size_t)(ks*44 + nb*NTL))*64*8;
    unsigned short* dst = sm.B[bb];
    if (tid < NTL*64) {
      __builtin_amdgcn_global_load_lds(
          (const __attribute__((address_space(1))) unsigned int*)(src + tid*8),
          (__attribute__((address_space(3))) unsigned int*)(dst + tid*8),
          16, 0, 0);
    }
  };
  auto stage1 = [&](int ks, fvec4& fa, fvec4& fb) {
    int k0 = ks*32 + akq;
    fa = (fvec4){0,0,0,0};
    fb = (fvec4){0,0,0,0};
    int t0 = k0/100, d0 = k0 - t0*100;
    unsigned wi0 = sm.widx[arow][t0];
    if (wi0 != 0xFFFFu)
      fa = *(const fvec4*)(word_table + (size_t)wi0*100 + d0);
    int k4 = k0 + 4;
    int t1 = k4/100, d1 = k4 - t1*100;
    unsigned wi1 = sm.widx[arow][t1];
    if (wi1 != 0xFFFFu)
      fb = *(const fvec4*)(word_table + (size_t)wi1*100 + d1);
  };
  auto stage2 = [&](fvec4 fa, fvec4 fb, int ab) {
    uint4 pk;
    pk.x = (unsigned)f2bf(fa[0]) | ((unsigned)f2bf(fa[1]) << 16);
    pk.y = (unsigned)f2bf(fa[2]) | ((unsigned)f2bf(fa[3]) << 16);
    pk.z = (unsigned)f2bf(fb[0]) | ((unsigned)f2bf(fb[1]) << 16);
    pk.w = (unsigned)f2bf(fb[2]) | ((unsigned)f2bf(fb[3]) << 16);
    ((uint4*)sm.A[ab])[tid] = pk;
  };
  auto compute = [&](int bb) {
    const bf16x8* Af = (const bf16x8*)sm.A[bb];
    const bf16x8* Bf = (const bf16x8*)sm.B[bb];
    bf16x8 a = Af[w*64 + lane];
#pragma unroll
    for (int j = 0; j < NTL; ++j) {
      bf16x8 b = Bf[j*64 + lane];
      acc[j] = __builtin_amdgcn_mfma_f32_16x16x32_bf16(a, b, acc[j], 0, 0, 0);
    }
  };

  issueB(0, 0);
  __syncthreads();
  { fvec4 fa, fb; stage1(0, fa, fb); stage2(fa, fb, 0); }
  __syncthreads();

  int buf = 0;
  for (int ks = 0; ks < KS1; ++ks) {
    const bool pre = (ks + 1 < KS1);
    fvec4 fa, fb;
    if (pre) { issueB(ks + 1, buf ^ 1); stage1(ks + 1, fa, fb); }
    compute(buf);
    if (pre) stage2(fa, fb, buf ^ 1);
    __syncthreads();
    buf ^= 1;
  }

  const int lr = (lane >> 4) << 2;
  const int lc = lane & 15;
#pragma unroll
  for (int j = 0; j < NTL; ++j) {
#pragma unroll
    for (int r = 0; r < 4; ++r) {
      size_t row = (size_t)rowbase + w*16 + lr + r;
      int col = nb*BN1 + j*16 + lc;
      __builtin_nontemporal_store(f2bf(acc[j][r]), hw + row*704 + col);
    }
  }
}

// ================= SPLIT PATH kernel 2: logits + softmax =================
struct SM2 {
  union { unsigned short h3[64*72]; float lg[64*96]; } u;  // 24,576 B
  unsigned char pidx[64][8];
  unsigned char didx[64][8];
  float bo_l[96];
};

__launch_bounds__(512, 6)
__global__ void logits_sm(const int* __restrict__ pos_idx,
                          const int* __restrict__ dep_idx,
                          const unsigned short* __restrict__ hw,
                          const unsigned short* __restrict__ PTb,
                          const unsigned short* __restrict__ DTb,
                          const float* __restrict__ hbias,
                          const unsigned short* __restrict__ WoP,
                          const float* __restrict__ bo,
                          float* __restrict__ out) {
  __shared__ SM2 sm;
  const int tid = threadIdx.x;
  const int lane = tid & 63;
  const int w = tid >> 6;
  const int blockRow = blockIdx.x * 64;

  if (tid < 448) {
    int r = tid / 7, t = tid - r*7;
    size_t gidx = (size_t)(blockRow + r)*7 + t;
    sm.pidx[r][t] = (unsigned char)pos_idx[gidx];
    sm.didx[r][t] = (unsigned char)dep_idx[gidx];
  }
  if (tid < 96) sm.bo_l[tid] = (tid < OUTC) ? bo[tid] : 0.f;

  f32x4 c2[3];
#pragma unroll
  for (int jn = 0; jn < 3; ++jn) c2[jn] = (f32x4){0,0,0,0};
  const int mt2 = w >> 1;
  const int nb2 = (w & 1)*3;
  const bf16x8* WoF = (const bf16x8*)WoP;
  const int r2  = tid >> 3;
  const int seg = tid & 7;

  __syncthreads();

  for (int c = 0; c < 11; ++c) {
    int col = c*64 + seg*8;
    uint4 hwv = *(const uint4*)(hw + (size_t)(blockRow + r2)*704 + col);
    float s[8];
    {
      float4 hb0 = *(const float4*)(hbias + col);
      float4 hb1 = *(const float4*)(hbias + col + 4);
      s[0]=hb0.x; s[1]=hb0.y; s[2]=hb0.z; s[3]=hb0.w;
      s[4]=hb1.x; s[5]=hb1.y; s[6]=hb1.z; s[7]=hb1.w;
    }
#pragma unroll
    for (int t = 0; t < 7; ++t) {
      int p = sm.pidx[r2][t];
      addbf8(s, *(const uint4*)(PTb + ((size_t)(t*NPOS + p))*704 + col));
      int dd = sm.didx[r2][t];
      addbf8(s, *(const uint4*)(DTb + ((size_t)(t*NDEP + dd))*704 + col));
    }
    unsigned short o8[8];
    {
      float hv[8];
      hv[0]=s[0]+bf2f((unsigned short)(hwv.x & 0xFFFF));
      hv[1]=s[1]+bf2f((unsigned short)(hwv.x >> 16));
      hv[2]=s[2]+bf2f((unsigned short)(hwv.y & 0xFFFF));
      hv[3]=s[3]+bf2f((unsigned short)(hwv.y >> 16));
      hv[4]=s[4]+bf2f((unsigned short)(hwv.z & 0xFFFF));
      hv[5]=s[5]+bf2f((unsigned short)(hwv.z >> 16));
      hv[6]=s[6]+bf2f((unsigned short)(hwv.w & 0xFFFF));
      hv[7]=s[7]+bf2f((unsigned short)(hwv.w >> 16));
#pragma unroll
      for (int i = 0; i < 8; ++i) { float h = hv[i]; o8[i] = f2bf(h*h*h); }
    }
    *(uint4*)(sm.u.h3 + r2*72 + seg*8) = *(const uint4*)o8;
    __syncthreads();

#pragma unroll
    for (int ksl = 0; ksl < 2; ++ksl) {
      bf16x8 a = *(const bf16x8*)(sm.u.h3 + (mt2*16 + (lane & 15))*72 + ksl*32 + ((lane >> 4) << 3));
      int ks2 = c*2 + ksl;
#pragma unroll
      for (int jn = 0; jn < 3; ++jn) {
        bf16x8 b = WoF[(size_t)(ks2*6 + nb2 + jn)*64 + lane];
        c2[jn] = __builtin_amdgcn_mfma_f32_16x16x32_bf16(a, b, c2[jn], 0, 0, 0);
      }
    }
    __syncthreads();
  }

  {
    float* lg = sm.u.lg;
    const int lr = ((lane >> 4) << 2), lc = lane & 15;
#pragma unroll
    for (int jn = 0; jn < 3; ++jn)
#pragma unroll
      for (int r = 0; r < 4; ++r)
        lg[(mt2*16 + lr + r)*96 + (nb2 + jn)*16 + lc] = c2[jn][r];
  }
  __syncthreads();
  {
    const float* lg = sm.u.lg;
    int row = tid >> 3, sgl = tid & 7;
    const float4* lp = (const float4*)(lg + row*96 + sgl*12);
    float4 xa = lp[0], xb = lp[1], xc = lp[2];
    float x[12] = {xa.x,xa.y,xa.z,xa.w, xb.x,xb.y,xb.z,xb.w, xc.x,xc.y,xc.z,xc.w};
    int cb = sgl*12;
    float mx = -1e30f;
#pragma unroll
    for (int i = 0; i < 12; ++i) {
      int cc = cb + i;
      x[i] += sm.bo_l[cc];
      mx = fmaxf(mx, (cc < OUTC) ? x[i] : -1e30f);
    }
    mx = fmaxf(mx, __shfl_xor(mx, 1, 8));
    mx = fmaxf(mx, __shfl_xor(mx, 2, 8));
    mx = fmaxf(mx, __shfl_xor(mx, 4, 8));
    float e[12]; float sum = 0.f;
#pragma unroll
    for (int i = 0; i < 12; ++i) {
      int cc = cb + i;
      e[i] = (cc < OUTC) ? __expf(x[i] - mx) : 0.f;
      sum += e[i];
    }
    sum += __shfl_xor(sum, 1, 8);
    sum += __shfl_xor(sum, 2, 8);
    sum += __shfl_xor(sum, 4, 8);
    float inv = 1.0f / sum;
    float* op = out + (size_t)(blockRow + row)*OUTC;
#pragma unroll
    for (int i = 0; i < 12; ++i) {
      int cc = cb + i;
      if (cc < OUTC) __builtin_nontemporal_store(e[i]*inv, op + cc);
    }
  }
}

// ================= FALLBACK: Round-1 fused dp_main (HW-proven, 204.6 us) =========
struct SMF {
  union {
    struct { unsigned short A[2][4*64*8]; unsigned short Bb[2][44*64*8]; } mm; // 98,304 B
    struct { unsigned short h3[64*712]; float logits[64*96]; } ep;             // 115,712 B
  } u;
  int widx[64][8];
  int pidxs[64][8];
  int didxs[64][8];
  float bo_l[96];
};

__launch_bounds__(512, 2)
__global__ void dp_fused(const int* __restrict__ word_idx,
                         const int* __restrict__ pos_idx,
                         const int* __restrict__ dep_idx,
                         const float* __restrict__ word_table,
                         const unsigned short* __restrict__ WwP,
                         const unsigned short* __restrict__ WoP,
                         const unsigned short* __restrict__ PTb,
                         const unsigned short* __restrict__ DTb,
                         const float* __restrict__ hbias,
                         const float* __restrict__ bo,
                         float* __restrict__ out) {
  __shared__ SMF sm;
  const int tid = threadIdx.x;
  const int lane = tid & 63;
  const int w = tid >> 6;
  const int blockRow = blockIdx.x * BMF;

  if (tid < 448) {
    int r = tid / 7, t = tid - r*7;
    int g = (blockRow + r)*7 + t;
    sm.widx[r][t]  = word_idx[g];
    sm.pidxs[r][t] = pos_idx[g];
    sm.didxs[r][t] = dep_idx[g];
  }
  if (tid < 96) sm.bo_l[tid] = (tid < OUTC) ? bo[tid] : 0.f;

  f32x4 acc0[11], acc1[11];
#pragma unroll
  for (int j = 0; j < 11; ++j) { acc0[j] = (f32x4){0,0,0,0}; acc1[j] = (f32x4){0,0,0,0}; }

  __syncthreads();

  auto issueB = [&](int ks, int buf) {
    const unsigned short* src = WwP + (size_t)ks*(44*64*8);
    unsigned short* dst = sm.u.mm.Bb[buf];
#pragma unroll
    for (int it = 0; it < 6; ++it) {
      int slot = it*512 + tid;
      if (slot < 44*64) {
        __builtin_amdgcn_global_load_lds(
            (const __attribute__((address_space(1))) unsigned int*)(src + slot*8),
            (__attribute__((address_space(3))) unsigned int*)(dst + slot*8),
            16, 0, 0);
      }
    }
  };
  auto gatherA = [&](int ks, float4& fa, float4& fb) {
    int mt = tid >> 6;
    int l = tid & 63;
    int row = mt*16 + (l & 15);
    int k0 = ks*32 + (l >> 4)*8;
    int t0 = k0 / 100, d0 = k0 - t0*100;
    fa = make_float4(0.f,0.f,0.f,0.f);
    fb = make_float4(0.f,0.f,0.f,0.f);
    {
      int wi = sm.widx[row][t0];
      if (wi >= 0) fa = *(const float4*)(word_table + (size_t)wi*100 + d0);
    }
    int k4 = k0 + 4; int t1 = k4 / 100, d1 = k4 - t1*100;
    if (t1 < 7) {
      int wi = sm.widx[row][t1];
      if (wi >= 0) fb = *(const float4*)(word_table + (size_t)wi*100 + d1);
    }
  };
  auto writeA = [&](int buf, float4 fa, float4 fb) {
    unsigned short v[8];
    v[0]=f2bf(fa.x); v[1]=f2bf(fa.y); v[2]=f2bf(fa.z); v[3]=f2bf(fa.w);
    v[4]=f2bf(fb.x); v[5]=f2bf(fb.y); v[6]=f2bf(fb.z); v[7]=f2bf(fb.w);
    ((uint4*)sm.u.mm.A[buf])[tid] = *(const uint4*)v;
  };
  const int mtb = (w >> 2) * 2;
  const int ntb = (w & 3) * 11;
  auto compute = [&](int buf) {
    const bf16x8* Af = (const bf16x8*)sm.u.mm.A[buf];
    const bf16x8* Bf = (const bf16x8*)sm.u.mm.Bb[buf];
    bf16x8 a0 = Af[(mtb + 0)*64 + lane];
    bf16x8 a1 = Af[(mtb + 1)*64 + lane];
#pragma unroll
    for (int j = 0; j < 11; ++j) {
      bf16x8 b = Bf[(ntb + j)*64 + lane];
      acc0[j] = __builtin_amdgcn_mfma_f32_16x16x32_bf16(a0, b, acc0[j], 0, 0, 0);
      acc1[j] = __builtin_amdgcn_mfma_f32_16x16x32_bf16(a1, b, acc1[j], 0, 0, 0);
    }
  };

  issueB(0, 0);
  if (tid < 256) {
    float4 fa, fb;
    gatherA(0, fa, fb);
    writeA(0, fa, fb);
  }
  __syncthreads();

  int buf = 0;
  for (int ks = 0; ks < KS1; ++ks) {
    float4 na, nb;
    const bool pre = (ks + 1 < KS1);
    if (pre) {
      issueB(ks + 1, buf ^ 1);
      if (tid < 256) gatherA(ks + 1, na, nb);
    }
    compute(buf);
    if (pre && tid < 256) writeA(buf ^ 1, na, nb);
    __syncthreads();
    buf ^= 1;
  }

  {
    unsigned short* h3 = sm.u.ep.h3;
#pragma unroll 1
    for (int it = 0; it < 11; ++it) {
      int v = it*512 + tid;
      int row = v / 88;
      int c8 = v - row*88;
      int cb = c8*8;
      float s0[8];
      float4 hb0 = *(const float4*)(hbias + cb);
      float4 hb1 = *(const float4*)(hbias + cb + 4);
      s0[0]=hb0.x; s0[1]=hb0.y; s0[2]=hb0.z; s0[3]=hb0.w;
      s0[4]=hb1.x; s0[5]=hb1.y; s0[6]=hb1.z; s0[7]=hb1.w;
#pragma unroll
      for (int t = 0; t < 7; ++t) {
        int p = sm.pidxs[row][t];
        addbf8(s0, *(const uint4*)(PTb + ((size_t)(t*NPOS + p))*704 + cb));
        int dd = sm.didxs[row][t];
        addbf8(s0, *(const uint4*)(DTb + ((size_t)(t*NDEP + dd))*704 + cb));
      }
      unsigned short o[8];
#pragma unroll
      for (int j = 0; j < 8; ++j) o[j] = f2bf(s0[j]);
      *(uint4*)(h3 + row*712 + cb) = *(const uint4*)o;
    }
  }
  __syncthreads();

  {
    unsigned short* h3 = sm.u.ep.h3;
    const int lr = (lane >> 4)*4, lc = lane & 15;
#pragma unroll
    for (int j = 0; j < 11; ++j) {
      int col = (ntb + j)*16 + lc;
      {
        int rb = (mtb + 0)*16 + lr;
#pragma unroll
        for (int r = 0; r < 4; ++r) {
          int off = (rb + r)*712 + col;
          float h = acc0[j][r] + bf2f(h3[off]);
          h3[off] = f2bf(h*h*h);
        }
      }
      {
        int rb = (mtb + 1)*16 + lr;
#pragma unroll
        for (int r = 0; r < 4; ++r) {
          int off = (rb + r)*712 + col;
          float h = acc1[j][r] + bf2f(h3[off]);
          h3[off] = f2bf(h*h*h);
        }
      }
    }
  }
  __syncthreads();

  {
    const unsigned short* h3 = sm.u.ep.h3;
    int mt = w >> 1;
    int nb2 = (w & 1)*3;
    f32x4 c2[3];
#pragma unroll
    for (int jn = 0; jn < 3; ++jn) c2[jn] = (f32x4){0,0,0,0};
    const bf16x8* WoF = (const bf16x8*)WoP;
    bf16x8 bfr[3];
#pragma unroll
    for (int jn = 0; jn < 3; ++jn) bfr[jn] = WoF[(size_t)(nb2 + jn)*64 + lane];
    const int arow = mt*16 + (lane & 15);
    const int koff = (lane >> 4)*8;
    for (int ks = 0; ks < KS1; ++ks) {
      bf16x8 a = *(const bf16x8*)(h3 + arow*712 + ks*32 + koff);
      bf16x8 bn[3];
      if (ks < KS1-1) {
#pragma unroll
        for (int jn = 0; jn < 3; ++jn) bn[jn] = WoF[((size_t)(ks+1)*6 + nb2 + jn)*64 + lane];
      }
#pragma unroll
      for (int jn = 0; jn < 3; ++jn)
        c2[jn] = __builtin_amdgcn_mfma_f32_16x16x32_bf16(a, bfr[jn], c2[jn], 0, 0, 0);
      if (ks < KS1-1) {
#pragma unroll
        for (int jn = 0; jn < 3; ++jn) bfr[jn] = bn[jn];
      }
    }
    float* lg = sm.u.ep.logits;
    const int lr = (lane >> 4)*4, lc = lane & 15;
#pragma unroll
    for (int jn = 0; jn < 3; ++jn)
#pragma unroll
      for (int r = 0; r < 4; ++r)
        lg[(mt*16 + lr + r)*96 + (nb2 + jn)*16 + lc] = c2[jn][r];
  }
  __syncthreads();

  {
    const float* lg = sm.u.ep.logits;
    int row = tid >> 3, s = tid & 7;
    const float4* lp = (const float4*)(lg + row*96 + s*12);
    float4 xa = lp[0], xb = lp[1], xc = lp[2];
    float x[12] = {xa.x,xa.y,xa.z,xa.w, xb.x,xb.y,xb.z,xb.w, xc.x,xc.y,xc.z,xc.w};
    int cb = s*12;
    float mx = -1e30f;
#pragma unroll
    for (int i = 0; i < 12; ++i) {
      int c = cb + i;
      x[i] += sm.bo_l[c];
      mx = fmaxf(mx, (c < OUTC) ? x[i] : -1e30f);
    }
    mx = fmaxf(mx, __shfl_xor(mx, 1, 8));
    mx = fmaxf(mx, __shfl_xor(mx, 2, 8));
    mx = fmaxf(mx, __shfl_xor(mx, 4, 8));
    float e[12]; float sum = 0.f;
#pragma unroll
    for (int i = 0; i < 12; ++i) {
      int c = cb + i;
      e[i] = (c < OUTC) ? __expf(x[i] - mx) : 0.f;
      sum += e[i];
    }
    sum += __shfl_xor(sum, 1, 8);
    sum += __shfl_xor(sum, 2, 8);
    sum += __shfl_xor(sum, 4, 8);
    float inv = 1.0f / sum;
    float* op = out + (size_t)(blockRow + row)*OUTC;
#pragma unroll
    for (int i = 0; i < 12; ++i) {
      int c = cb + i;
      if (c < OUTC) op[c] = e[i]*inv;
    }
  }
}

extern "C" void kernel_launch(void* const* d_in, const int* in_sizes, int n_in,
                              void* d_out, int out_size, void* d_ws, size_t ws_size,
                              hipStream_t stream) {
  const int*   word_idx   = (const int*)d_in[0];
  const int*   pos_idx    = (const int*)d_in[1];
  const int*   dep_idx    = (const int*)d_in[2];
  const float* word_table = (const float*)d_in[3];
  const float* pos_table  = (const float*)d_in[4];
  const float* dep_table  = (const float*)d_in[5];
  const float* Ww = (const float*)d_in[6];
  const float* bw = (const float*)d_in[7];
  const float* Wp = (const float*)d_in[8];
  const float* bp = (const float*)d_in[9];
  const float* Wd = (const float*)d_in[10];
  const float* bd = (const float*)d_in[11];
  const float* Wo = (const float*)d_in[12];
  const float* bo = (const float*)d_in[13];
  float* out = (float*)d_out;

  char* ws = (char*)d_ws;
  unsigned short* WwP   = (unsigned short*)(ws + O_WWP);
  unsigned short* WoP   = (unsigned short*)(ws + O_WOP);
  unsigned short* PTb   = (unsigned short*)(ws + O_PTB);
  unsigned short* DTb   = (unsigned short*)(ws + O_DTB);
  float*          hbias = (float*)(ws + O_HB);
  unsigned short* hw    = (unsigned short*)(ws + O_HW);

  // shared prep (~2.2 MB of ws)
  pack_w<<<KS1*44, 64, 0, stream>>>(Ww, WwP, 700, 700, 44);
  pack_w<<<KS1*6,  64, 0, stream>>>(Wo, WoP, 700, OUTC, 6);
  pack_tbl<<<(7*NPOS*704 + 255)/256, 256, 0, stream>>>(pos_table, Wp, PTb, NPOS, 7*NPOS*704);
  pack_tbl<<<(7*NDEP*704 + 255)/256, 256, 0, stream>>>(dep_table, Wd, DTb, NDEP, 7*NDEP*704);
  bias_sum<<<3, 256, 0, stream>>>(bw, bp, bd, hbias);

  // ws_size is constant across calls -> branch is graph-capture-stable
  if (ws_size >= WS_NEED_SPLIT) {
    gemm_hw<<<1024, 1024, 0, stream>>>(word_idx, word_table, WwP, hw);
    logits_sm<<<1024, 512, 0, stream>>>(pos_idx, dep_idx, hw, PTb, DTb, hbias, WoP, bo, out);
  } else {
    dp_fused<<<65536/BMF, 512, 0, stream>>>(word_idx, pos_idx, dep_idx, word_table,
                                            WwP, WoP, PTb, DTb, hbias, bo, out);
  }
}

// Round 11
// 365.766 us; speedup vs baseline: 2.3683x; 2.3683x over previous
//
#include <hip/hip_runtime.h>
#include <stdint.h>

// ---------------- problem constants ----------------
#define OUTC 93
#define KS1 22           // K=704 / 32  (word GEMM k-steps)
#define NPOS 50
#define NDEP 45
// kernel1 tile
#define BM1 128
#define BN1 176
#define NTL 11           // local n-tiles (176/16)

typedef __attribute__((ext_vector_type(8))) short bf16x8;
typedef __attribute__((ext_vector_type(4))) float f32x4;
typedef __attribute__((ext_vector_type(4))) float fvec4;

// ws layout (bytes), all 16B-aligned
#define O_WWP  0
#define SZ_WWP (KS1*44*64*8*2)              // 991,232
#define O_WOP  (O_WWP + SZ_WWP)
#define SZ_WOP (KS1*6*64*8*2)               // 270,336
#define O_PTB  (O_WOP + SZ_WOP)
#define SZ_PTB (7*NPOS*704*2)               // 492,800
#define O_DTB  (O_PTB + SZ_PTB)
#define SZ_DTB (7*NDEP*704*2)               // 443,520
#define O_HB   (O_DTB + SZ_DTB)
#define SZ_HB  (704*4)                      // 2,816
#define O_HW   (O_HB + SZ_HB)               // hw: 65536*704*2 = 92,274,688

__device__ __forceinline__ unsigned short f2bf(float f) {
  unsigned u = __float_as_uint(f);
  u += 0x7FFFu + ((u >> 16) & 1u);          // RNE
  return (unsigned short)(u >> 16);
}
__device__ __forceinline__ float bf2f(unsigned short h) {
  return __uint_as_float(((unsigned)h) << 16);
}
__device__ __forceinline__ void addbf8(float* s, const uint4 v) {
  unsigned u0 = v.x, u1 = v.y, u2 = v.z, u3 = v.w;
  s[0] += __uint_as_float(u0 << 16);
  s[1] += __uint_as_float(u0 & 0xFFFF0000u);
  s[2] += __uint_as_float(u1 << 16);
  s[3] += __uint_as_float(u1 & 0xFFFF0000u);
  s[4] += __uint_as_float(u2 << 16);
  s[5] += __uint_as_float(u2 & 0xFFFF0000u);
  s[6] += __uint_as_float(u3 << 16);
  s[7] += __uint_as_float(u3 & 0xFFFF0000u);
}

// ---- prep: pack f32 [Ksrc x Nsrc] into MFMA B-fragment layout [ks][nt][lane][8]
__global__ void pack_w(const float* __restrict__ W, unsigned short* __restrict__ out,
                       int Ksrc, int Nsrc, int ntiles) {
  int blk = blockIdx.x;
  int ks = blk / ntiles, nt = blk - ks*ntiles;
  int l = threadIdx.x;
  int n = nt*16 + (l & 15);
  int k0 = ks*32 + ((l >> 4) << 3);
  unsigned short v[8];
#pragma unroll
  for (int j = 0; j < 8; ++j) {
    int k = k0 + j;
    float f = (k < Ksrc && n < Nsrc) ? W[k*Nsrc + n] : 0.f;
    v[j] = f2bf(f);
  }
  ((uint4*)out)[blk*64 + l] = *(const uint4*)v;
}

// ---- prep: PT[t][p][h] = sum_d tbl[p][d] * W[t*100+d][h], bf16, h padded to 704
__global__ void pack_tbl(const float* __restrict__ tbl, const float* __restrict__ W,
                         unsigned short* __restrict__ out, int P, int total) {
  int id = blockIdx.x*256 + threadIdx.x;
  if (id >= total) return;
  int hp = id % 704;
  int tp = id / 704;
  int p = tp % P, t = tp / P;
  float acc = 0.f;
  if (hp < 700) {
    const float* tr = tbl + p*100;
    const float* wc = W + t*100*700 + hp;
#pragma unroll 4
    for (int d = 0; d < 100; ++d) acc += tr[d] * wc[d*700];
  }
  out[id] = f2bf(acc);
}

__global__ void bias_sum(const float* __restrict__ a, const float* __restrict__ b,
                         const float* __restrict__ c, float* __restrict__ o) {
  int i = blockIdx.x*256 + threadIdx.x;
  if (i < 704) o[i] = (i < 700) ? (a[i] + b[i] + c[i]) : 0.f;
}

// ================= kernel 1: hw = gather(word) @ Ww  =================
// BM=128, BN=176; 2048 blocks = 512 mb x 4 nb; 512 thr = 8 waves.
// wave w owns mtile w (16 rows) x 11 ntiles; acc = 11 f32x4 = 44 AGPR.
// LDS 40,960 B -> 2 blocks/CU co-resident (latency cover across barriers).
struct SM1 {
  unsigned short A[2][8*64*8];    // 16,384 B
  unsigned short B[2][NTL*64*8];  // 22,528 B
  unsigned short widx[BM1][8];    //  2,048 B  (col 7 = 0xFFFF sentinel pad)
};  // 40,960 B

__launch_bounds__(512, 4)
__global__ void gemm_hw(const int* __restrict__ word_idx,
                        const float* __restrict__ word_table,
                        const unsigned short* __restrict__ WwP,
                        unsigned short* __restrict__ hw) {
  __shared__ SM1 sm;
  const int tid = threadIdx.x;
  const int lane = tid & 63;
  const int w = tid >> 6;

  // bijective XCD swizzle (2048 % 8 == 0): full rows + full WwP per XCD
  int D = blockIdx.x;
  int g = (D & 7)*256 + (D >> 3);
  const int nb = g & 3;
  const int mb = g >> 2;
  const int rowbase = mb * BM1;

  // ---- stage word indices for 128 rows ----
#pragma unroll
  for (int i = tid; i < BM1*8; i += 512) {
    int r = i >> 3, c = i & 7;
    unsigned short v = 0xFFFFu;
    if (c < 7) {
      int wi = word_idx[(size_t)(rowbase + r)*7 + c];
      v = (wi < 0) ? 0xFFFFu : (unsigned short)wi;
    }
    sm.widx[r][c] = v;
  }

  // A staging map: thread t covers frag slot t (mtile t>>6, lane t&63, 8 k-elems)
  const int amt  = tid >> 6;                 // 0..7
  const int al   = tid & 63;
  const int arow = amt*16 + (al & 15);
  const int akq  = (al >> 4) << 3;           // k offset 0/8/16/24

  f32x4 acc[NTL];
#pragma unroll
  for (int j = 0; j < NTL; ++j) acc[j] = (f32x4){0,0,0,0};

  auto issueB = [&](int ks, int bb) {
    const unsigned short* src = WwP + ((size_t)(ks*44 + nb*NTL))*64*8;
    unsigned short* dst = sm.B[bb];
#pragma unroll
    for (int it = 0; it < 2; ++it) {
      int slot = it*512 + tid;
      if (slot < NTL*64) {
        __builtin_amdgcn_global_load_lds(
            (const __attribute__((address_space(1))) unsigned int*)(src + slot*8),
            (__attribute__((address_space(3))) unsigned int*)(dst + slot*8),
            16, 0, 0);
      }
    }
  };
  auto stage1 = [&](int ks, fvec4& fa, fvec4& fb) {
    int k0 = ks*32 + akq;                    // < 704, multiple of 8
    fa = (fvec4){0,0,0,0};
    fb = (fvec4){0,0,0,0};
    int t0 = k0/100, d0 = k0 - t0*100;       // d0 mult of 4, within row
    unsigned wi0 = sm.widx[arow][t0];
    if (wi0 != 0xFFFFu)
      fa = *(const fvec4*)(word_table + (size_t)wi0*100 + d0);
    int k4 = k0 + 4;
    int t1 = k4/100, d1 = k4 - t1*100;       // t1 may be 7 -> sentinel col
    unsigned wi1 = sm.widx[arow][t1];
    if (wi1 != 0xFFFFu)
      fb = *(const fvec4*)(word_table + (size_t)wi1*100 + d1);
  };
  auto stage2 = [&](fvec4 fa, fvec4 fb, int ab) {
    uint4 pk;
    pk.x = (unsigned)f2bf(fa[0]) | ((unsigned)f2bf(fa[1]) << 16);
    pk.y = (unsigned)f2bf(fa[2]) | ((unsigned)f2bf(fa[3]) << 16);
    pk.z = (unsigned)f2bf(fb[0]) | ((unsigned)f2bf(fb[1]) << 16);
    pk.w = (unsigned)f2bf(fb[2]) | ((unsigned)f2bf(fb[3]) << 16);
    ((uint4*)sm.A[ab])[tid] = pk;
  };
  auto compute = [&](int bb) {
    const bf16x8* Af = (const bf16x8*)sm.A[bb];
    const bf16x8* Bf = (const bf16x8*)sm.B[bb];
    bf16x8 a = Af[w*64 + lane];
#pragma unroll
    for (int j = 0; j < NTL; ++j) {
      bf16x8 b = Bf[j*64 + lane];
      acc[j] = __builtin_amdgcn_mfma_f32_16x16x32_bf16(a, b, acc[j], 0, 0, 0);
    }
  };

  // ---- prologue ----
  issueB(0, 0);
  __syncthreads();                 // widx + B(0) visible
  { fvec4 fa, fb; stage1(0, fa, fb); stage2(fa, fb, 0); }
  __syncthreads();                 // A(0) visible

  // ---- main K loop: 22 steps, dbuf A/B, one barrier/step ----
  int buf = 0;
  for (int ks = 0; ks < KS1; ++ks) {
    const bool pre = (ks + 1 < KS1);
    fvec4 fa, fb;
    if (pre) { issueB(ks + 1, buf ^ 1); stage1(ks + 1, fa, fb); }
    compute(buf);
    if (pre) stage2(fa, fb, buf ^ 1);
    __syncthreads();
    buf ^= 1;
  }

  // ---- store hw tile (bf16, row-major [65536][704]); cached so L2 merges ----
  const int lr = (lane >> 4) << 2;           // row offset within mtile
  const int lc = lane & 15;                  // col offset within ntile
#pragma unroll
  for (int j = 0; j < NTL; ++j) {
#pragma unroll
    for (int r = 0; r < 4; ++r) {
      size_t row = (size_t)rowbase + w*16 + lr + r;
      int col = nb*BN1 + j*16 + lc;
      hw[row*704 + col] = f2bf(acc[j][r]);
    }
  }
}

// ================= kernel 2: logits + softmax =================
// 64 rows/block, 512 thr = 8 waves. Stream 11 chunks of 64 cols:
// h3 = (hw + hbias + sum_t PT[t,p] + DT[t,d])^3 -> LDS -> 2 MFMA k-steps vs Wo.
// NOTE: no min-waves in launch_bounds — R10 showed (512,6) forced VGPR=40 and
// ~1.3 GB of scratch spill traffic in the chunk loop.
struct SM2 {
  union { unsigned short h3[64*72]; float lg[64*96]; } u;  // 24,576 B
  unsigned char pidx[64][8];
  unsigned char didx[64][8];
  float bo_l[96];
};

__launch_bounds__(512)
__global__ void logits_sm(const int* __restrict__ pos_idx,
                          const int* __restrict__ dep_idx,
                          const unsigned short* __restrict__ hw,
                          const unsigned short* __restrict__ PTb,
                          const unsigned short* __restrict__ DTb,
                          const float* __restrict__ hbias,
                          const unsigned short* __restrict__ WoP,
                          const float* __restrict__ bo,
                          float* __restrict__ out) {
  __shared__ SM2 sm;
  const int tid = threadIdx.x;
  const int lane = tid & 63;
  const int w = tid >> 6;
  const int blockRow = blockIdx.x * 64;

  if (tid < 448) {
    int r = tid / 7, t = tid - r*7;
    size_t gidx = (size_t)(blockRow + r)*7 + t;
    sm.pidx[r][t] = (unsigned char)pos_idx[gidx];
    sm.didx[r][t] = (unsigned char)dep_idx[gidx];
  }
  if (tid < 96) sm.bo_l[tid] = (tid < OUTC) ? bo[tid] : 0.f;

  f32x4 c2[3];
#pragma unroll
  for (int jn = 0; jn < 3; ++jn) c2[jn] = (f32x4){0,0,0,0};
  const int mt2 = w >> 1;            // 4 row-tiles of 16
  const int nb2 = (w & 1)*3;         // Wo n-tile group
  const bf16x8* WoF = (const bf16x8*)WoP;
  const int r2  = tid >> 3;          // 0..63  (row for staging)
  const int seg = tid & 7;           // 0..7   (8-col segment)

  __syncthreads();                   // pidx/didx visible

  for (int c = 0; c < 11; ++c) {
    // ---- build h3 chunk: rows 64 x cols [c*64, c*64+64) ----
    int col = c*64 + seg*8;
    uint4 hwv = *(const uint4*)(hw + (size_t)(blockRow + r2)*704 + col);
    float s[8];
    {
      float4 hb0 = *(const float4*)(hbias + col);
      float4 hb1 = *(const float4*)(hbias + col + 4);
      s[0]=hb0.x; s[1]=hb0.y; s[2]=hb0.z; s[3]=hb0.w;
      s[4]=hb1.x; s[5]=hb1.y; s[6]=hb1.z; s[7]=hb1.w;
    }
#pragma unroll
    for (int t = 0; t < 7; ++t) {
      int p = sm.pidx[r2][t];
      addbf8(s, *(const uint4*)(PTb + ((size_t)(t*NPOS + p))*704 + col));
      int dd = sm.didx[r2][t];
      addbf8(s, *(const uint4*)(DTb + ((size_t)(t*NDEP + dd))*704 + col));
    }
    unsigned short o8[8];
    {
      float hv[8];
      hv[0]=s[0]+bf2f((unsigned short)(hwv.x & 0xFFFF));
      hv[1]=s[1]+bf2f((unsigned short)(hwv.x >> 16));
      hv[2]=s[2]+bf2f((unsigned short)(hwv.y & 0xFFFF));
      hv[3]=s[3]+bf2f((unsigned short)(hwv.y >> 16));
      hv[4]=s[4]+bf2f((unsigned short)(hwv.z & 0xFFFF));
      hv[5]=s[5]+bf2f((unsigned short)(hwv.z >> 16));
      hv[6]=s[6]+bf2f((unsigned short)(hwv.w & 0xFFFF));
      hv[7]=s[7]+bf2f((unsigned short)(hwv.w >> 16));
#pragma unroll
      for (int i = 0; i < 8; ++i) { float h = hv[i]; o8[i] = f2bf(h*h*h); }
    }
    *(uint4*)(sm.u.h3 + r2*72 + seg*8) = *(const uint4*)o8;
    __syncthreads();

    // ---- 2 MFMA k-steps over this chunk ----
#pragma unroll
    for (int ksl = 0; ksl < 2; ++ksl) {
      bf16x8 a = *(const bf16x8*)(sm.u.h3 + (mt2*16 + (lane & 15))*72 + ksl*32 + ((lane >> 4) << 3));
      int ks2 = c*2 + ksl;
#pragma unroll
      for (int jn = 0; jn < 3; ++jn) {
        bf16x8 b = WoF[(size_t)(ks2*6 + nb2 + jn)*64 + lane];
        c2[jn] = __builtin_amdgcn_mfma_f32_16x16x32_bf16(a, b, c2[jn], 0, 0, 0);
      }
    }
    __syncthreads();                 // done reading h3 before next chunk overwrites
  }

  // ---- logits to LDS, softmax (93 classes, 8 thr/row) ----
  {
    float* lg = sm.u.lg;
    const int lr = ((lane >> 4) << 2), lc = lane & 15;
#pragma unroll
    for (int jn = 0; jn < 3; ++jn)
#pragma unroll
      for (int r = 0; r < 4; ++r)
        lg[(mt2*16 + lr + r)*96 + (nb2 + jn)*16 + lc] = c2[jn][r];
  }
  __syncthreads();
  {
    const float* lg = sm.u.lg;
    int row = tid >> 3, sgl = tid & 7;
    const float4* lp = (const float4*)(lg + row*96 + sgl*12);
    float4 xa = lp[0], xb = lp[1], xc = lp[2];
    float x[12] = {xa.x,xa.y,xa.z,xa.w, xb.x,xb.y,xb.z,xb.w, xc.x,xc.y,xc.z,xc.w};
    int cb = sgl*12;
    float mx = -1e30f;
#pragma unroll
    for (int i = 0; i < 12; ++i) {
      int cc = cb + i;
      x[i] += sm.bo_l[cc];
      mx = fmaxf(mx, (cc < OUTC) ? x[i] : -1e30f);
    }
    mx = fmaxf(mx, __shfl_xor(mx, 1, 8));
    mx = fmaxf(mx, __shfl_xor(mx, 2, 8));
    mx = fmaxf(mx, __shfl_xor(mx, 4, 8));
    float e[12]; float sum = 0.f;
#pragma unroll
    for (int i = 0; i < 12; ++i) {
      int cc = cb + i;
      e[i] = (cc < OUTC) ? __expf(x[i] - mx) : 0.f;
      sum += e[i];
    }
    sum += __shfl_xor(sum, 1, 8);
    sum += __shfl_xor(sum, 2, 8);
    sum += __shfl_xor(sum, 4, 8);
    float inv = 1.0f / sum;
    float* op = out + (size_t)(blockRow + row)*OUTC;
#pragma unroll
    for (int i = 0; i < 12; ++i) {
      int cc = cb + i;
      if (cc < OUTC) op[cc] = e[i]*inv;
    }
  }
}

extern "C" void kernel_launch(void* const* d_in, const int* in_sizes, int n_in,
                              void* d_out, int out_size, void* d_ws, size_t ws_size,
                              hipStream_t stream) {
  const int*   word_idx   = (const int*)d_in[0];
  const int*   pos_idx    = (const int*)d_in[1];
  const int*   dep_idx    = (const int*)d_in[2];
  const float* word_table = (const float*)d_in[3];
  const float* pos_table  = (const float*)d_in[4];
  const float* dep_table  = (const float*)d_in[5];
  const float* Ww = (const float*)d_in[6];
  const float* bw = (const float*)d_in[7];
  const float* Wp = (const float*)d_in[8];
  const float* bp = (const float*)d_in[9];
  const float* Wd = (const float*)d_in[10];
  const float* bd = (const float*)d_in[11];
  const float* Wo = (const float*)d_in[12];
  const float* bo = (const float*)d_in[13];
  float* out = (float*)d_out;

  char* ws = (char*)d_ws;
  unsigned short* WwP   = (unsigned short*)(ws + O_WWP);
  unsigned short* WoP   = (unsigned short*)(ws + O_WOP);
  unsigned short* PTb   = (unsigned short*)(ws + O_PTB);
  unsigned short* DTb   = (unsigned short*)(ws + O_DTB);
  float*          hbias = (float*)(ws + O_HB);
  unsigned short* hw    = (unsigned short*)(ws + O_HW);

  pack_w<<<KS1*44, 64, 0, stream>>>(Ww, WwP, 700, 700, 44);
  pack_w<<<KS1*6,  64, 0, stream>>>(Wo, WoP, 700, OUTC, 6);
  pack_tbl<<<(7*NPOS*704 + 255)/256, 256, 0, stream>>>(pos_table, Wp, PTb, NPOS, 7*NPOS*704);
  pack_tbl<<<(7*NDEP*704 + 255)/256, 256, 0, stream>>>(dep_table, Wd, DTb, NDEP, 7*NDEP*704);
  bias_sum<<<3, 256, 0, stream>>>(bw, bp, bd, hbias);

  gemm_hw<<<2048, 512, 0, stream>>>(word_idx, word_table, WwP, hw);
  logits_sm<<<1024, 512, 0, stream>>>(pos_idx, dep_idx, hw, PTb, DTb, hbias, WoP, bo, out);
}